// Round 2
// baseline (5399.321 us; speedup 1.0000x reference)
//
#include <hip/hip_runtime.h>

// GraphSAGE 2-layer forward, MI355X baseline (fp32 everywhere).
// Layer1: agg1 = mean_agg(x) [20000,300]; h1 = relu([x|agg1] @ [Ws1;Wn1] + b1)
// Layer2: t2 = h1 @ Wn2 (aggregate AFTER projection: mean_agg commutes with @)
//         out = h1 @ Ws2 + mean_agg(t2) + b2

constexpr int NN = 20000;   // nodes
constexpr int NE = 640000;  // edges
constexpr int F0 = 300;     // in feats
constexpr int F1 = 512;     // hidden
constexpr int F2 = 256;     // classes

// ---------------- degree ----------------
__global__ void deg_kernel(const int* __restrict__ dst, float* __restrict__ deg) {
    int e = blockIdx.x * 256 + threadIdx.x;
    if (e < NE) atomicAdd(&deg[dst[e]], 1.0f);
}

// ---------------- scatter-add aggregations (atomics) ----------------
__global__ void scatter1_kernel(const float* __restrict__ x, const int* __restrict__ src,
                                const int* __restrict__ dst, float* __restrict__ agg) {
    long idx = (long)blockIdx.x * 256 + threadIdx.x;
    constexpr int CH = F0 / 4;  // 75 float4 chunks per row
    int e = (int)(idx / CH);
    int c = (int)(idx % CH);
    if (e >= NE) return;
    int s = src[e], d = dst[e];
    float4 v = *(const float4*)(x + (long)s * F0 + c * 4);
    float* o = agg + (long)d * F0 + c * 4;
    atomicAdd(o + 0, v.x); atomicAdd(o + 1, v.y);
    atomicAdd(o + 2, v.z); atomicAdd(o + 3, v.w);
}

__global__ void scatter2_kernel(const float* __restrict__ t, const int* __restrict__ src,
                                const int* __restrict__ dst, float* __restrict__ agg) {
    long idx = (long)blockIdx.x * 256 + threadIdx.x;
    int e = (int)(idx >> 6);    // 64 float4 chunks per row (256 feats)
    int c = (int)(idx & 63);
    if (e >= NE) return;
    int s = src[e], d = dst[e];
    float4 v = *(const float4*)(t + (long)s * F2 + c * 4);
    float* o = agg + (long)d * F2 + c * 4;
    atomicAdd(o + 0, v.x); atomicAdd(o + 1, v.y);
    atomicAdd(o + 2, v.z); atomicAdd(o + 3, v.w);
}

// buf[m][*] *= 1/max(deg[m],1)  (d4 = feats/4)
__global__ void scale_rows_kernel(float* __restrict__ buf, const float* __restrict__ deg, int d4) {
    long idx = (long)blockIdx.x * 256 + threadIdx.x;
    if (idx >= (long)NN * d4) return;
    int m = (int)(idx / d4);
    float inv = 1.0f / fmaxf(deg[m], 1.0f);
    float4* p = (float4*)buf + idx;
    float4 v = *p;
    v.x *= inv; v.y *= inv; v.z *= inv; v.w *= inv;
    *p = v;
}

// ---------------- fp32 tiled GEMM ----------------
// MODE 0: C = A1 @ B1
// MODE 1: C = relu([A1 | A2] @ [B1 ; B2] + bias)   (K1 = boundary, both parts ld = K1)
// MODE 2: C = A1 @ B1 + bias + addend
constexpr int BM = 128, BN = 128, BK = 8;

template<int MODE>
__global__ __launch_bounds__(256) void gemm_kernel(
    const float* __restrict__ A1, const float* __restrict__ A2,
    const float* __restrict__ B1, const float* __restrict__ B2,
    const float* __restrict__ bias, const float* __restrict__ addend,
    float* __restrict__ C, int M, int N, int Ktot, int K1)
{
    __shared__ float As[BK][BM + 4];
    __shared__ float Bs[BK][BN + 4];

    const int t = threadIdx.x;
    const int tx = t & 15, ty = t >> 4;
    const int m0 = blockIdx.x * BM;
    const int n0 = blockIdx.y * BN;

    float acc[8][8];
    #pragma unroll
    for (int i = 0; i < 8; ++i)
        #pragma unroll
        for (int j = 0; j < 8; ++j) acc[i][j] = 0.f;

    const int ar = t >> 1;        // 0..127: row within A tile
    const int ah = (t & 1) * 4;   // 0 or 4: col within BK
    const int bk = t >> 5;        // 0..7:   row within B tile
    const int bc = (t & 31) * 4;  // col within B tile

    for (int k0 = 0; k0 < Ktot; k0 += BK) {
        // stage A tile (transposed into LDS)
        {
            int m = m0 + ar;
            int k = k0 + ah;
            float4 v = make_float4(0.f, 0.f, 0.f, 0.f);
            if (m < M) {
                if (MODE == 1) {
                    if (k < K1) v = *(const float4*)(A1 + (long)m * K1 + k);
                    else        v = *(const float4*)(A2 + (long)m * K1 + (k - K1));
                } else {
                    v = *(const float4*)(A1 + (long)m * Ktot + k);
                }
            }
            As[ah + 0][ar] = v.x; As[ah + 1][ar] = v.y;
            As[ah + 2][ar] = v.z; As[ah + 3][ar] = v.w;
        }
        // stage B tile
        {
            int k = k0 + bk;
            int n = n0 + bc;
            float4 v;
            if (MODE == 1) {
                if (k < K1) v = *(const float4*)(B1 + (long)k * N + n);
                else        v = *(const float4*)(B2 + (long)(k - K1) * N + n);
            } else {
                v = *(const float4*)(B1 + (long)k * N + n);
            }
            *(float4*)&Bs[bk][bc] = v;
        }
        __syncthreads();
        #pragma unroll
        for (int kk = 0; kk < BK; ++kk) {
            float4 a0 = *(const float4*)&As[kk][ty * 8];
            float4 a1 = *(const float4*)&As[kk][ty * 8 + 4];
            float4 b0 = *(const float4*)&Bs[kk][tx * 8];
            float4 b1 = *(const float4*)&Bs[kk][tx * 8 + 4];
            float a[8] = {a0.x, a0.y, a0.z, a0.w, a1.x, a1.y, a1.z, a1.w};
            float b[8] = {b0.x, b0.y, b0.z, b0.w, b1.x, b1.y, b1.z, b1.w};
            #pragma unroll
            for (int i = 0; i < 8; ++i)
                #pragma unroll
                for (int j = 0; j < 8; ++j)
                    acc[i][j] = fmaf(a[i], b[j], acc[i][j]);
        }
        __syncthreads();
    }

    #pragma unroll
    for (int i = 0; i < 8; ++i) {
        int m = m0 + ty * 8 + i;
        if (m >= M) continue;
        #pragma unroll
        for (int j = 0; j < 8; ++j) {
            int n = n0 + tx * 8 + j;
            float v = acc[i][j];
            if (MODE == 1) v = fmaxf(v + bias[n], 0.f);
            if (MODE == 2) v = v + bias[n] + addend[(long)m * N + n];
            C[(long)m * N + n] = v;
        }
    }
}

extern "C" void kernel_launch(void* const* d_in, const int* in_sizes, int n_in,
                              void* d_out, int out_size, void* d_ws, size_t ws_size,
                              hipStream_t stream) {
    const float* x   = (const float*)d_in[0];
    const float* Ws1 = (const float*)d_in[1];
    const float* Wn1 = (const float*)d_in[2];
    const float* b1  = (const float*)d_in[3];
    const float* Ws2 = (const float*)d_in[4];
    const float* Wn2 = (const float*)d_in[5];
    const float* b2  = (const float*)d_in[6];
    const int* src   = (const int*)d_in[7];
    const int* dst   = (const int*)d_in[8];
    float* out = (float*)d_out;

    // workspace layout (bytes, all 16B aligned):
    //   deg  : 0          .. 80,000          (20000 f32)
    //   agg1 : 80,000     .. 24,080,000      (20000x300 f32) — reused as t2 later
    //   h1   : 24,080,000 .. 65,040,000      (20000x512 f32)
    //   agg2 : 65,040,000 .. 85,520,000      (20000x256 f32)
    char* ws = (char*)d_ws;
    float* deg  = (float*)(ws);
    float* agg1 = (float*)(ws + 80000);
    float* h1   = (float*)(ws + 80000 + 24000000);
    float* agg2 = (float*)(ws + 80000 + 24000000 + 40960000);

    hipMemsetAsync(deg,  0, 80000,    stream);
    hipMemsetAsync(agg1, 0, 24000000, stream);
    hipMemsetAsync(agg2, 0, 20480000, stream);

    deg_kernel<<<NE / 256, 256, 0, stream>>>(dst, deg);

    // layer 1: aggregate x, then fused concat-GEMM with relu+bias
    scatter1_kernel<<<(int)(((long)NE * (F0 / 4) + 255) / 256), 256, 0, stream>>>(x, src, dst, agg1);
    scale_rows_kernel<<<(NN * (F0 / 4) + 255) / 256, 256, 0, stream>>>(agg1, deg, F0 / 4);

    dim3 g1((NN + BM - 1) / BM, F1 / BN);
    gemm_kernel<1><<<g1, 256, 0, stream>>>(x, agg1, Ws1, Wn1, b1, nullptr, h1, NN, F1, 2 * F0, F0);

    // layer 2: project first (t2 = h1 @ Wn2), then aggregate t2, then self-GEMM + add
    float* t2 = agg1;  // agg1 dead now
    dim3 g2((NN + BM - 1) / BM, F2 / BN);
    gemm_kernel<0><<<g2, 256, 0, stream>>>(h1, nullptr, Wn2, nullptr, nullptr, nullptr, t2, NN, F2, F1, 0);

    scatter2_kernel<<<(int)(((long)NE * (F2 / 4)) / 256), 256, 0, stream>>>(t2, src, dst, agg2);
    scale_rows_kernel<<<(NN * (F2 / 4)) / 256, 256, 0, stream>>>(agg2, deg, F2 / 4);

    gemm_kernel<2><<<g2, 256, 0, stream>>>(h1, nullptr, Ws2, nullptr, b2, agg2, out, NN, F2, F1, 0);
}

// Round 3
// 795.524 us; speedup vs baseline: 6.7871x; 6.7871x over previous
//
#include <hip/hip_runtime.h>

// GraphSAGE 2-layer forward, MI355X. Round 2: CSR gather instead of atomic scatter.
// Layer1: agg1 = mean_agg(x) [20000,300]; h1 = relu([x|agg1] @ [Ws1;Wn1] + b1)
// Layer2: t2 = h1 @ Wn2; out = mean_agg(t2)  (gathered directly into d_out);
//         out = h1 @ Ws2 + b2 + out  (in-place addend)

constexpr int NN = 20000;   // nodes
constexpr int NE = 640000;  // edges
constexpr int F0 = 300;     // in feats
constexpr int F1 = 512;     // hidden
constexpr int F2 = 256;     // classes

// ---------------- CSR build ----------------
__global__ void count_kernel(const int* __restrict__ dst, int* __restrict__ cnt) {
    int e = blockIdx.x * 256 + threadIdx.x;
    if (e < NE) atomicAdd(&cnt[dst[e]], 1);
}

// single-block exclusive scan of cnt[0..NN) -> row_ptr[0..NN], also cursor = row_ptr
__global__ __launch_bounds__(1024) void scan_kernel(const int* __restrict__ cnt,
                                                    int* __restrict__ row_ptr,
                                                    int* __restrict__ cursor) {
    constexpr int CH = (NN + 1023) / 1024;  // 20
    __shared__ int part[1024];
    const int t = threadIdx.x;
    int base = t * CH;
    int s = 0;
    #pragma unroll
    for (int i = 0; i < CH; ++i) {
        int idx = base + i;
        if (idx < NN) s += cnt[idx];
    }
    part[t] = s;
    __syncthreads();
    // Hillis-Steele inclusive scan over 1024 partials
    #pragma unroll
    for (int off = 1; off < 1024; off <<= 1) {
        int v = (t >= off) ? part[t - off] : 0;
        __syncthreads();
        part[t] += v;
        __syncthreads();
    }
    int run = (t == 0) ? 0 : part[t - 1];  // exclusive prefix of this thread's segment
    #pragma unroll
    for (int i = 0; i < CH; ++i) {
        int idx = base + i;
        if (idx < NN) {
            row_ptr[idx] = run;
            cursor[idx] = run;
            run += cnt[idx];
        }
    }
    if (t == 1023) row_ptr[NN] = part[1023];
}

__global__ void fill_kernel(const int* __restrict__ src, const int* __restrict__ dst,
                            int* __restrict__ cursor, int* __restrict__ csr_src) {
    int e = blockIdx.x * 256 + threadIdx.x;
    if (e >= NE) return;
    int pos = atomicAdd(&cursor[dst[e]], 1);
    csr_src[pos] = src[e];
}

// ---------------- CSR mean-gather ----------------
// one thread per (node m, float4 chunk c); D4 = feats/4
template<int D4>
__global__ __launch_bounds__(256) void gather_kernel(const float* __restrict__ feat,
                                                     const int* __restrict__ row_ptr,
                                                     const int* __restrict__ csr_src,
                                                     float* __restrict__ outbuf) {
    long idx = (long)blockIdx.x * 256 + threadIdx.x;
    if (idx >= (long)NN * D4) return;
    int m = (int)(idx / D4);
    int c = (int)(idx % D4);
    int beg = row_ptr[m], end = row_ptr[m + 1];
    float4 acc = make_float4(0.f, 0.f, 0.f, 0.f);
    for (int e = beg; e < end; ++e) {
        int s = csr_src[e];
        float4 v = *(const float4*)(feat + (long)s * (D4 * 4) + c * 4);
        acc.x += v.x; acc.y += v.y; acc.z += v.z; acc.w += v.w;
    }
    float inv = 1.0f / fmaxf((float)(end - beg), 1.0f);
    acc.x *= inv; acc.y *= inv; acc.z *= inv; acc.w *= inv;
    *((float4*)(outbuf + (long)m * (D4 * 4) + c * 4)) = acc;
}

// ---------------- fp32 tiled GEMM ----------------
// MODE 0: C = A1 @ B1
// MODE 1: C = relu([A1 | A2] @ [B1 ; B2] + bias)   (K1 = boundary, both parts ld = K1)
// MODE 2: C = A1 @ B1 + bias + addend   (addend may alias C)
constexpr int BM = 128, BN = 128, BK = 8;

template<int MODE>
__global__ __launch_bounds__(256) void gemm_kernel(
    const float* __restrict__ A1, const float* __restrict__ A2,
    const float* __restrict__ B1, const float* __restrict__ B2,
    const float* __restrict__ bias, const float* __restrict__ addend,
    float* __restrict__ C, int M, int N, int Ktot, int K1)
{
    __shared__ float As[BK][BM + 4];
    __shared__ float Bs[BK][BN + 4];

    const int t = threadIdx.x;
    const int tx = t & 15, ty = t >> 4;
    const int m0 = blockIdx.x * BM;
    const int n0 = blockIdx.y * BN;

    float acc[8][8];
    #pragma unroll
    for (int i = 0; i < 8; ++i)
        #pragma unroll
        for (int j = 0; j < 8; ++j) acc[i][j] = 0.f;

    const int ar = t >> 1;        // 0..127: row within A tile
    const int ah = (t & 1) * 4;   // 0 or 4: col within BK
    const int bk = t >> 5;        // 0..7:   row within B tile
    const int bc = (t & 31) * 4;  // col within B tile

    for (int k0 = 0; k0 < Ktot; k0 += BK) {
        {
            int m = m0 + ar;
            int k = k0 + ah;
            float4 v = make_float4(0.f, 0.f, 0.f, 0.f);
            if (m < M) {
                if (MODE == 1) {
                    if (k < K1) v = *(const float4*)(A1 + (long)m * K1 + k);
                    else        v = *(const float4*)(A2 + (long)m * K1 + (k - K1));
                } else {
                    v = *(const float4*)(A1 + (long)m * Ktot + k);
                }
            }
            As[ah + 0][ar] = v.x; As[ah + 1][ar] = v.y;
            As[ah + 2][ar] = v.z; As[ah + 3][ar] = v.w;
        }
        {
            int k = k0 + bk;
            int n = n0 + bc;
            float4 v;
            if (MODE == 1) {
                if (k < K1) v = *(const float4*)(B1 + (long)k * N + n);
                else        v = *(const float4*)(B2 + (long)(k - K1) * N + n);
            } else {
                v = *(const float4*)(B1 + (long)k * N + n);
            }
            *(float4*)&Bs[bk][bc] = v;
        }
        __syncthreads();
        #pragma unroll
        for (int kk = 0; kk < BK; ++kk) {
            float4 a0 = *(const float4*)&As[kk][ty * 8];
            float4 a1 = *(const float4*)&As[kk][ty * 8 + 4];
            float4 b0 = *(const float4*)&Bs[kk][tx * 8];
            float4 b1 = *(const float4*)&Bs[kk][tx * 8 + 4];
            float a[8] = {a0.x, a0.y, a0.z, a0.w, a1.x, a1.y, a1.z, a1.w};
            float b[8] = {b0.x, b0.y, b0.z, b0.w, b1.x, b1.y, b1.z, b1.w};
            #pragma unroll
            for (int i = 0; i < 8; ++i)
                #pragma unroll
                for (int j = 0; j < 8; ++j)
                    acc[i][j] = fmaf(a[i], b[j], acc[i][j]);
        }
        __syncthreads();
    }

    #pragma unroll
    for (int i = 0; i < 8; ++i) {
        int m = m0 + ty * 8 + i;
        if (m >= M) continue;
        #pragma unroll
        for (int j = 0; j < 8; ++j) {
            int n = n0 + tx * 8 + j;
            float v = acc[i][j];
            if (MODE == 1) v = fmaxf(v + bias[n], 0.f);
            if (MODE == 2) v = v + bias[n] + addend[(long)m * N + n];
            C[(long)m * N + n] = v;
        }
    }
}

extern "C" void kernel_launch(void* const* d_in, const int* in_sizes, int n_in,
                              void* d_out, int out_size, void* d_ws, size_t ws_size,
                              hipStream_t stream) {
    const float* x   = (const float*)d_in[0];
    const float* Ws1 = (const float*)d_in[1];
    const float* Wn1 = (const float*)d_in[2];
    const float* b1  = (const float*)d_in[3];
    const float* Ws2 = (const float*)d_in[4];
    const float* Wn2 = (const float*)d_in[5];
    const float* b2  = (const float*)d_in[6];
    const int* src   = (const int*)d_in[7];
    const int* dst   = (const int*)d_in[8];
    float* out = (float*)d_out;

    // workspace layout (bytes, 16B aligned):
    //   row_ptr : 0          .. 80,064        (20001 i32)
    //   csr_src : 80,064     .. 2,640,064     (640000 i32)
    //   agg1/t2 : 2,640,064  .. 26,640,064    (20000x300 f32; t2 20000x256 fits)
    //   h1      : 26,640,064 .. 67,600,064    (20000x512 f32)
    //   cursor  : 67,600,064 .. 67,680,064    (20000 i32; counts then fill cursor)
    char* ws = (char*)d_ws;
    int*   row_ptr = (int*)(ws);
    int*   csr_src = (int*)(ws + 80064);
    float* agg1    = (float*)(ws + 2640064);
    float* h1      = (float*)(ws + 26640064);
    int*   cursor  = (int*)(ws + 67600064);

    // ---- CSR build (per launch; no static state allowed) ----
    hipMemsetAsync(cursor, 0, NN * sizeof(int), stream);
    count_kernel<<<(NE + 255) / 256, 256, 0, stream>>>(dst, cursor);
    scan_kernel<<<1, 1024, 0, stream>>>(cursor, row_ptr, cursor);
    fill_kernel<<<(NE + 255) / 256, 256, 0, stream>>>(src, dst, cursor, csr_src);

    // ---- layer 1: gather mean(x) -> agg1, then fused concat-GEMM + relu ----
    {
        long tot = (long)NN * (F0 / 4);
        gather_kernel<F0 / 4><<<(int)((tot + 255) / 256), 256, 0, stream>>>(x, row_ptr, csr_src, agg1);
    }
    dim3 g1((NN + BM - 1) / BM, F1 / BN);
    gemm_kernel<1><<<g1, 256, 0, stream>>>(x, agg1, Ws1, Wn1, b1, nullptr, h1, NN, F1, 2 * F0, F0);

    // ---- layer 2: t2 = h1 @ Wn2; out = mean_agg(t2); out = h1 @ Ws2 + b2 + out ----
    float* t2 = agg1;  // agg1 dead after GEMM1
    dim3 g2((NN + BM - 1) / BM, F2 / BN);
    gemm_kernel<0><<<g2, 256, 0, stream>>>(h1, nullptr, Wn2, nullptr, nullptr, nullptr, t2, NN, F2, F1, 0);

    {
        long tot = (long)NN * (F2 / 4);
        gather_kernel<F2 / 4><<<(int)((tot + 255) / 256), 256, 0, stream>>>(t2, row_ptr, csr_src, out);
    }
    gemm_kernel<2><<<g2, 256, 0, stream>>>(h1, nullptr, Ws2, nullptr, b2, out, out, NN, F2, F1, 0);
}

// Round 4
// 459.296 us; speedup vs baseline: 11.7556x; 1.7320x over previous
//
#include <hip/hip_runtime.h>

// GraphSAGE 2-layer forward, MI355X. Round 3: f16 MFMA GEMMs + f16 gathers.
// A1b[20000][640] f16 = [x | mean_agg(x) | 0-pad]; h1 = relu(A1b @ Wt1^T + b1) (f16)
// t2 = h1 @ Wn2 (f16); out = mean_agg(t2) (f32); out = h1 @ Ws2 + b2 + out (f32)

typedef _Float16 f16;
typedef _Float16 f16x4 __attribute__((ext_vector_type(4)));
typedef _Float16 f16x8 __attribute__((ext_vector_type(8)));
typedef float f32x4 __attribute__((ext_vector_type(4)));

constexpr int NN = 20000;   // nodes
constexpr int NE = 640000;  // edges
constexpr int F0 = 300;     // in feats
constexpr int F1 = 512;     // hidden
constexpr int F2 = 256;     // classes
constexpr int KP1 = 640;    // padded concat-K for layer 1 (multiple of 64)

// ---------------- input conversion ----------------
// x f32 -> A1b cols 0..299 (f16); zero cols 600..639
__global__ void conv_x_kernel(const float* __restrict__ x, f16* __restrict__ A1b) {
    long idx = (long)blockIdx.x * 256 + threadIdx.x;  // m*80 + c
    if (idx >= (long)NN * 80) return;
    int m = (int)(idx / 80), c = (int)(idx % 80);
    if (c < 75) {
        float4 v = *(const float4*)(x + (long)m * F0 + 4 * c);
        f16x4 h = {(f16)v.x, (f16)v.y, (f16)v.z, (f16)v.w};
        *(f16x4*)(A1b + (long)m * KP1 + 4 * c) = h;
    } else {
        f16x8 z = {};
        *(f16x8*)(A1b + (long)m * KP1 + 600 + (c - 75) * 8) = z;
    }
}

// Wt1[n][k] (f16, [512][640]) = k<300 ? Ws1[k][n] : k<600 ? Wn1[k-300][n] : 0
__global__ void prep_w1_kernel(const float* __restrict__ Ws1, const float* __restrict__ Wn1,
                               f16* __restrict__ Wt1) {
    int idx = blockIdx.x * 256 + threadIdx.x;
    if (idx >= F1 * KP1) return;
    int n = idx / KP1, k = idx % KP1;
    float v = 0.f;
    if (k < 300) v = Ws1[k * F1 + n];
    else if (k < 600) v = Wn1[(k - 300) * F1 + n];
    Wt1[idx] = (f16)v;
}

// Wt[n][k] ([256][512]) = W[k][n] ([512][256])
__global__ void prep_w2_kernel(const float* __restrict__ W, f16* __restrict__ Wt) {
    int idx = blockIdx.x * 256 + threadIdx.x;
    if (idx >= F2 * F1) return;
    int n = idx / F1, k = idx % F1;
    Wt[idx] = (f16)W[k * F2 + n];
}

// ---------------- CSR build ----------------
__global__ void count_kernel(const int* __restrict__ dst, int* __restrict__ cnt) {
    int e = blockIdx.x * 256 + threadIdx.x;
    if (e < NE) atomicAdd(&cnt[dst[e]], 1);
}

__global__ __launch_bounds__(1024) void scan_kernel(const int* __restrict__ cnt,
                                                    int* __restrict__ row_ptr,
                                                    int* __restrict__ cursor) {
    constexpr int CH = (NN + 1023) / 1024;  // 20
    __shared__ int part[1024];
    const int t = threadIdx.x;
    int base = t * CH;
    int s = 0;
    #pragma unroll
    for (int i = 0; i < CH; ++i) {
        int idx = base + i;
        if (idx < NN) s += cnt[idx];
    }
    part[t] = s;
    __syncthreads();
    #pragma unroll
    for (int off = 1; off < 1024; off <<= 1) {
        int v = (t >= off) ? part[t - off] : 0;
        __syncthreads();
        part[t] += v;
        __syncthreads();
    }
    int run = (t == 0) ? 0 : part[t - 1];
    #pragma unroll
    for (int i = 0; i < CH; ++i) {
        int idx = base + i;
        if (idx < NN) {
            row_ptr[idx] = run;
            cursor[idx] = run;
            run += cnt[idx];
        }
    }
    if (t == 1023) row_ptr[NN] = part[1023];
}

__global__ void fill_kernel(const int* __restrict__ src, const int* __restrict__ dst,
                            int* __restrict__ cursor, int* __restrict__ csr_src) {
    int e = blockIdx.x * 256 + threadIdx.x;
    if (e >= NE) return;
    int pos = atomicAdd(&cursor[dst[e]], 1);
    csr_src[pos] = src[e];
}

// ---------------- gathers (mean over in-neighbors) ----------------
// gather1: reads A1b cols 0..299 (f16), writes mean into A1b cols 300..599 (f16)
__global__ __launch_bounds__(256) void gather1_kernel(const int* __restrict__ row_ptr,
                                                      const int* __restrict__ csr,
                                                      f16* __restrict__ A1b) {
    long idx = (long)blockIdx.x * 256 + threadIdx.x;  // m*75 + c
    if (idx >= (long)NN * 75) return;
    int m = (int)(idx / 75), c = (int)(idx % 75);
    int beg = row_ptr[m], end = row_ptr[m + 1];
    float a0 = 0.f, a1 = 0.f, a2 = 0.f, a3 = 0.f;
    for (int e = beg; e < end; ++e) {
        int s = csr[e];
        f16x4 v = *(const f16x4*)(A1b + (long)s * KP1 + 4 * c);
        a0 += (float)v[0]; a1 += (float)v[1]; a2 += (float)v[2]; a3 += (float)v[3];
    }
    float inv = 1.0f / fmaxf((float)(end - beg), 1.0f);
    f16x4 h = {(f16)(a0 * inv), (f16)(a1 * inv), (f16)(a2 * inv), (f16)(a3 * inv)};
    *(f16x4*)(A1b + (long)m * KP1 + 300 + 4 * c) = h;
}

// gather2: reads t2 (f16 [NN][256]), writes f32 mean into out
__global__ __launch_bounds__(256) void gather2_kernel(const int* __restrict__ row_ptr,
                                                      const int* __restrict__ csr,
                                                      const f16* __restrict__ t2,
                                                      float* __restrict__ out) {
    long idx = (long)blockIdx.x * 256 + threadIdx.x;  // m*32 + c
    if (idx >= (long)NN * 32) return;
    int m = (int)(idx / 32), c = (int)(idx % 32);
    int beg = row_ptr[m], end = row_ptr[m + 1];
    float a[8] = {0.f, 0.f, 0.f, 0.f, 0.f, 0.f, 0.f, 0.f};
    for (int e = beg; e < end; ++e) {
        int s = csr[e];
        f16x8 v = *(const f16x8*)(t2 + (long)s * F2 + 8 * c);
        #pragma unroll
        for (int j = 0; j < 8; ++j) a[j] += (float)v[j];
    }
    float inv = 1.0f / fmaxf((float)(end - beg), 1.0f);
    float4 w0 = {a[0] * inv, a[1] * inv, a[2] * inv, a[3] * inv};
    float4 w1 = {a[4] * inv, a[5] * inv, a[6] * inv, a[7] * inv};
    *(float4*)(out + (long)m * F2 + 8 * c) = w0;
    *(float4*)(out + (long)m * F2 + 8 * c + 4) = w1;
}

// ---------------- f16 MFMA GEMM ----------------
// C = A[M][K] @ Bt[N][K]^T, 128x128 tile, BK=64, 4 waves (2x2), 4x4 16x16x32 frags.
// MODE 0: out_f16 = C            MODE 1: out_f16 = relu(C + bias)
// MODE 2: out_f32 = C + bias + out_f32 (in-place addend)
template<int MODE>
__global__ __launch_bounds__(256) void hgemm_kernel(
    const f16* __restrict__ A, const f16* __restrict__ Bt,
    const float* __restrict__ bias, float* __restrict__ out_f32,
    f16* __restrict__ out_f16, int M, int N, int K)
{
    __shared__ f16 As[128][72];  // 64 + 8 pad
    __shared__ f16 Bs[128][72];

    const int t = threadIdx.x;
    const int lane = t & 63, wave = t >> 6;
    const int wr = wave >> 1, wc = wave & 1;
    const int m0 = blockIdx.x * 128, n0 = blockIdx.y * 128;
    const int r = t >> 1, kh = (t & 1) * 32;  // staging: row, k-half

    f32x4 acc[4][4] = {};

    for (int k0 = 0; k0 < K; k0 += 64) {
        // stage A tile (guard M), 4x 16B per thread
        {
            const f16* ga = A + (long)(m0 + r) * K + k0 + kh;
            bool mok = (m0 + r) < M;
            f16x8 v0 = mok ? *(const f16x8*)(ga + 0)  : (f16x8){};
            f16x8 v1 = mok ? *(const f16x8*)(ga + 8)  : (f16x8){};
            f16x8 v2 = mok ? *(const f16x8*)(ga + 16) : (f16x8){};
            f16x8 v3 = mok ? *(const f16x8*)(ga + 24) : (f16x8){};
            *(f16x8*)&As[r][kh + 0]  = v0;
            *(f16x8*)&As[r][kh + 8]  = v1;
            *(f16x8*)&As[r][kh + 16] = v2;
            *(f16x8*)&As[r][kh + 24] = v3;
        }
        // stage B tile (N is multiple of 128, no guard)
        {
            const f16* gb = Bt + (long)(n0 + r) * K + k0 + kh;
            f16x8 v0 = *(const f16x8*)(gb + 0);
            f16x8 v1 = *(const f16x8*)(gb + 8);
            f16x8 v2 = *(const f16x8*)(gb + 16);
            f16x8 v3 = *(const f16x8*)(gb + 24);
            *(f16x8*)&Bs[r][kh + 0]  = v0;
            *(f16x8*)&Bs[r][kh + 8]  = v1;
            *(f16x8*)&Bs[r][kh + 16] = v2;
            *(f16x8*)&Bs[r][kh + 24] = v3;
        }
        __syncthreads();
        #pragma unroll
        for (int kk = 0; kk < 2; ++kk) {
            f16x8 af[4], bf[4];
            #pragma unroll
            for (int i = 0; i < 4; ++i)
                af[i] = *(const f16x8*)&As[wr * 64 + i * 16 + (lane & 15)][kk * 32 + (lane >> 4) * 8];
            #pragma unroll
            for (int j = 0; j < 4; ++j)
                bf[j] = *(const f16x8*)&Bs[wc * 64 + j * 16 + (lane & 15)][kk * 32 + (lane >> 4) * 8];
            #pragma unroll
            for (int i = 0; i < 4; ++i)
                #pragma unroll
                for (int j = 0; j < 4; ++j)
                    acc[i][j] = __builtin_amdgcn_mfma_f32_16x16x32_f16(af[i], bf[j], acc[i][j], 0, 0, 0);
        }
        __syncthreads();
    }

    // epilogue: C/D layout col = lane&15, row = (lane>>4)*4 + q  [m89-verified]
    const int cr = (lane >> 4) * 4, cc = lane & 15;
    #pragma unroll
    for (int i = 0; i < 4; ++i) {
        #pragma unroll
        for (int j = 0; j < 4; ++j) {
            int n = n0 + wc * 64 + j * 16 + cc;
            float b = (MODE != 0) ? bias[n] : 0.f;
            #pragma unroll
            for (int q = 0; q < 4; ++q) {
                int m = m0 + wr * 64 + i * 16 + cr + q;
                if (m >= M) continue;
                float v = acc[i][j][q];
                if (MODE == 1) {
                    v = fmaxf(v + b, 0.f);
                    out_f16[(long)m * N + n] = (f16)v;
                } else if (MODE == 0) {
                    out_f16[(long)m * N + n] = (f16)v;
                } else {
                    float* p = out_f32 + (long)m * N + n;
                    *p = v + b + *p;
                }
            }
        }
    }
}

extern "C" void kernel_launch(void* const* d_in, const int* in_sizes, int n_in,
                              void* d_out, int out_size, void* d_ws, size_t ws_size,
                              hipStream_t stream) {
    const float* x   = (const float*)d_in[0];
    const float* Ws1 = (const float*)d_in[1];
    const float* Wn1 = (const float*)d_in[2];
    const float* b1  = (const float*)d_in[3];
    const float* Ws2 = (const float*)d_in[4];
    const float* Wn2 = (const float*)d_in[5];
    const float* b2  = (const float*)d_in[6];
    const int* src   = (const int*)d_in[7];
    const int* dst   = (const int*)d_in[8];
    float* out = (float*)d_out;

    // workspace layout (bytes, 16B aligned):
    char* ws = (char*)d_ws;
    int* row_ptr = (int*)(ws);                      // 20001 i32    [0 .. 80,064)
    int* csr_src = (int*)(ws + 80064);              // 640000 i32   [80,064 .. 2,640,064)
    int* cursor  = (int*)(ws + 2640064);            // 20000 i32    [2,640,064 .. 2,720,064)
    f16* A1b     = (f16*)(ws + 2720064);            // 20000x640    [2,720,064 .. 28,320,064)
    f16* h1      = (f16*)(ws + 28320064);           // 20000x512    [28,320,064 .. 48,800,064)
    f16* t2      = (f16*)(ws + 48800064);           // 20000x256    [48,800,064 .. 59,040,064)
    f16* Wt1     = (f16*)(ws + 59040064);           // 512x640      [59,040,064 .. 59,695,424)
    f16* Wt2s    = (f16*)(ws + 59695424);           // 256x512      [59,695,424 .. 59,957,568)
    f16* Wt2n    = (f16*)(ws + 59957568);           // 256x512      [59,957,568 .. 60,219,712)

    // ---- prep: conversions + CSR build (independent) ----
    conv_x_kernel<<<(int)(((long)NN * 80) / 256), 256, 0, stream>>>(x, A1b);
    prep_w1_kernel<<<(F1 * KP1) / 256, 256, 0, stream>>>(Ws1, Wn1, Wt1);
    prep_w2_kernel<<<(F2 * F1) / 256, 256, 0, stream>>>(Ws2, Wt2s);
    prep_w2_kernel<<<(F2 * F1) / 256, 256, 0, stream>>>(Wn2, Wt2n);

    hipMemsetAsync(cursor, 0, NN * sizeof(int), stream);
    count_kernel<<<(NE + 255) / 256, 256, 0, stream>>>(dst, cursor);
    scan_kernel<<<1, 1024, 0, stream>>>(cursor, row_ptr, cursor);
    fill_kernel<<<(NE + 255) / 256, 256, 0, stream>>>(src, dst, cursor, csr_src);

    // ---- layer 1 ----
    gather1_kernel<<<(int)(((long)NN * 75 + 255) / 256), 256, 0, stream>>>(row_ptr, csr_src, A1b);
    dim3 g1((NN + 127) / 128, F1 / 128);
    hgemm_kernel<1><<<g1, 256, 0, stream>>>(A1b, Wt1, b1, nullptr, h1, NN, F1, KP1);

    // ---- layer 2 ----
    dim3 g2((NN + 127) / 128, F2 / 128);
    hgemm_kernel<0><<<g2, 256, 0, stream>>>(h1, Wt2n, nullptr, nullptr, t2, NN, F2, F1);
    gather2_kernel<<<(int)(((long)NN * 32) / 256), 256, 0, stream>>>(row_ptr, csr_src, t2, out);
    hgemm_kernel<2><<<g2, 256, 0, stream>>>(h1, Wt2s, b2, out, nullptr, NN, F2, F1);
}